// Round 9
// baseline (360.918 us; speedup 1.0000x reference)
//
#include <hip/hip_runtime.h>
#include <cstdint>
#include <cstddef>

#define K_CODES 1024
#define D_DIM   64
#define T_SZ    2048
#define N_ROWS  32768
#define BCT     2097152

typedef const __attribute__((address_space(1))) uint32_t* gp1_t;
typedef __attribute__((address_space(3))) uint32_t*       lp3_t;
typedef __attribute__((ext_vector_type(8))) short         short8;  // 8 bf16
typedef __attribute__((ext_vector_type(4))) float         f32x4;
typedef __attribute__((ext_vector_type(4))) int           i32x4;

// ws layout (bytes):
//   [0,     4096):   hist[1024] int     (zeroed by k_prep)
//   [4096,  4104):   loss_sum double    (zeroed by k_prep)
//   [4112,  4116):   done int           (zeroed by k_prep)
//   [8192,  12288):  esq[1024] float
//   [16384, 540672): Wpack bf16 [64ct][2ks][2hl][64lane][8j] ushort (256KB)

__device__ __forceinline__ ushort bf16_rne(float f) {
    uint32_t u = __builtin_bit_cast(uint32_t, f);
    u += 0x7FFFu + ((u >> 16) & 1u);
    return (ushort)(u >> 16);
}
__device__ __forceinline__ float bf16_f(ushort h) {
    uint32_t u = ((uint32_t)h) << 16;
    return __builtin_bit_cast(float, u);
}

// 8 threads per code: esq (fp64) + W packed into MFMA B-fragment bf16 hi/lo.
__global__ __launch_bounds__(256) void k_prep(const float* __restrict__ w,
                                              float* __restrict__ esq,
                                              ushort* __restrict__ wpack,
                                              int* __restrict__ hist,
                                              double* __restrict__ loss_sum,
                                              int* __restrict__ done) {
    const int gtid = blockIdx.x * 256 + threadIdx.x;   // 0..8191
    const int k = gtid >> 3, grp = gtid & 7;
    if (gtid < K_CODES) hist[gtid] = 0;
    if (gtid == 0) { loss_sum[0] = 0.0; done[0] = 0; }
    const int ct = k >> 4, cl = k & 15;
    double s = 0.0;
#pragma unroll
    for (int jj = 0; jj < 8; ++jj) {
        const int d = grp * 8 + jj;
        const float x = w[k * 64 + d];
        s = fma((double)x, (double)x, s);
        const ushort hi = bf16_rne(x);
        const ushort lo = bf16_rne(x - bf16_f(hi));
        const int ks = d >> 5, g = (d >> 3) & 3, j = d & 7;
        const int lane = g * 16 + cl;
        const size_t base = ((size_t)(ct * 2 + ks)) * 2;
        wpack[((base + 0) * 64 + lane) * 8 + j] = hi;
        wpack[((base + 1) * 64 + lane) * 8 + j] = lo;
    }
    s += __shfl_xor(s, 1); s += __shfl_xor(s, 2); s += __shfl_xor(s, 4);
    if (grp == 0) esq[k] = (float)s;
}

// MFMA mega-kernel: 1024 blocks x 256 thr (4 waves) -> 4 resident blocks/CU
// (LDS 37.5KB). Block = 32 rows x all 1024 codes. Wave w: tile = w&1 (16
// rows), half = w>>1 (512 codes). W streamed as 16 x 16KB chunks (2 ct per
// half), double-buffered via global_load_lds. Distances via 3 bf16-split
// MFMAs; per-half top-2 -> 4-candidate fp64 recheck decides the index.
// Last block computes perplexity+loss (fused k_final, device-scope atomics).
__global__ __launch_bounds__(256, 4) void k_argmin(
        const float* __restrict__ in, const float* __restrict__ w,
        const float* __restrict__ esq, const ushort* __restrict__ wpack,
        int* __restrict__ hist, double* __restrict__ loss_sum,
        int* __restrict__ done, float* __restrict__ qout,
        float* __restrict__ enc, float* __restrict__ out_loss,
        float* __restrict__ out_perp) {
    __shared__ __align__(16) ushort lds_b[2][8192];    // 2 x 16KB (reused later)
    __shared__ float  lds_esq[K_CODES];                // 4KB
    __shared__ int    smem_c[32 * 4];                  // [row][half*2 + {1st,2nd}]
    __shared__ int    fin_s[32];
    __shared__ double redd[4];
    __shared__ int    last_s;

    const int tid  = threadIdx.x;
    const int lane = tid & 63;
    const int wv   = tid >> 6;      // 0..3
    const int tile = wv & 1;        // which 16-row tile
    const int half = wv >> 1;       // which 512-code half
    const int cl   = lane & 15;     // col-in-tile / A-row-in-tile
    const int g    = lane >> 4;     // k-group
    const int n0   = blockIdx.x * 32;
    const int b    = n0 >> 11;
    const int t0   = n0 & (T_SZ - 1);
    const size_t bbase = (size_t)b * 131072;

#pragma unroll
    for (int r = 0; r < 4; ++r) lds_esq[r * 256 + tid] = esq[r * 256 + tid];

    // ---- A fragments (A-row = lane&15, k = g*8+j; same k-map as B ->
    // shared permutation cancels in the contraction) ----
    const int t_row = t0 + tile * 16 + cl;
    short8 ah[2], al[2];
#pragma unroll
    for (int ks = 0; ks < 2; ++ks) {
        short8 h, l;
#pragma unroll
        for (int j = 0; j < 8; ++j) {
            const int d = ks * 32 + g * 8 + j;
            const float x = in[bbase + (size_t)d * T_SZ + t_row];
            const ushort hb = bf16_rne(x);
            h[j] = (short)hb;
            l[j] = (short)bf16_rne(x - bf16_f(hb));
        }
        ah[ks] = h;
        al[ks] = l;
    }

    // chunk ch stages ct {2ch, 2ch+1} (half0) and {32+2ch, 33+2ch} (half1)
#define STAGEW(BUF, CH)                                                        \
    {                                                                          \
        _Pragma("unroll")                                                      \
        for (int r = 0; r < 4; ++r) {                                          \
            const int ct_src = (r < 2) ? (2 * (CH) + r) : (30 + 2 * (CH) + r); \
            const ushort* gsrc = wpack + (size_t)ct_src * 2048 + (size_t)tid * 8;\
            ushort* ldst = &lds_b[BUF][r * 2048 + tid * 8];                    \
            __builtin_amdgcn_global_load_lds((gp1_t)gsrc, (lp3_t)ldst, 16, 0, 0);\
        }                                                                      \
    }

    STAGEW(0, 0)
    __syncthreads();

    f32x4 m1v = {-1e30f, -1e30f, -1e30f, -1e30f};
    f32x4 m2v = {-1e30f, -1e30f, -1e30f, -1e30f};
    i32x4 i1v = {0, 0, 0, 0};
    i32x4 i2v = {0, 0, 0, 0};

    int buf = 0;
    for (int ch = 0; ch < 16; ++ch) {
        if (ch < 15) STAGEW(buf ^ 1, ch + 1)
        __builtin_amdgcn_s_setprio(1);
#pragma unroll
        for (int ctl = 0; ctl < 2; ++ctl) {
            const int c = (half * 32 + 2 * ch + ctl) * 16 + cl;
            const int slot = half * 2 + ctl;
            const float e2 = -0.5f * lds_esq[c];
            f32x4 accP = {e2, e2, e2, e2};
            f32x4 accQ = {0.f, 0.f, 0.f, 0.f};
#pragma unroll
            for (int ks = 0; ks < 2; ++ks) {
                const short8 bh = *(const short8*)&lds_b[buf][slot * 2048 + ((ks * 2 + 0) * 64 + lane) * 8];
                const short8 bl = *(const short8*)&lds_b[buf][slot * 2048 + ((ks * 2 + 1) * 64 + lane) * 8];
                accP = __builtin_amdgcn_mfma_f32_16x16x32_bf16(ah[ks], bh, accP, 0, 0, 0);
                accQ = __builtin_amdgcn_mfma_f32_16x16x32_bf16(ah[ks], bl, accQ, 0, 0, 0);
                accQ = __builtin_amdgcn_mfma_f32_16x16x32_bf16(al[ks], bh, accQ, 0, 0, 0);
            }
            // top-2 (maximize; ascending c + strict '>' keeps lowest index)
#pragma unroll
            for (int reg = 0; reg < 4; ++reg) {
                const float v = accP[reg] + accQ[reg];
                const bool gt1 = v > m1v[reg];
                const bool gt2 = v > m2v[reg];
                const float nm2 = gt1 ? m1v[reg] : (gt2 ? v : m2v[reg]);
                const int   ni2 = gt1 ? i1v[reg] : (gt2 ? c : i2v[reg]);
                m1v[reg] = gt1 ? v : m1v[reg];
                i1v[reg] = gt1 ? c : i1v[reg];
                m2v[reg] = nm2;
                i2v[reg] = ni2;
            }
        }
        __builtin_amdgcn_s_setprio(0);
        __syncthreads();   // drains STAGE vmcnt + protects buf swap
        buf ^= 1;
    }

    // ---- merge top-2 across the 16 lanes of each col-group ----
#pragma unroll
    for (int off = 1; off < 16; off <<= 1) {
#pragma unroll
        for (int reg = 0; reg < 4; ++reg) {
            const float pm1 = __shfl_xor(m1v[reg], off);
            const int   pi1 = __shfl_xor(i1v[reg], off);
            const float pm2 = __shfl_xor(m2v[reg], off);
            const int   pi2 = __shfl_xor(i2v[reg], off);
            const bool ours = (m1v[reg] > pm1) ||
                              (m1v[reg] == pm1 && i1v[reg] < pi1);
            float nm1, nm2; int ni1, ni2;
            if (ours) {
                nm1 = m1v[reg]; ni1 = i1v[reg];
                const bool pb = (pm1 > m2v[reg]) ||
                                (pm1 == m2v[reg] && pi1 < i2v[reg]);
                nm2 = pb ? pm1 : m2v[reg];
                ni2 = pb ? pi1 : i2v[reg];
            } else {
                nm1 = pm1; ni1 = pi1;
                const bool ob = (m1v[reg] > pm2) ||
                                (m1v[reg] == pm2 && i1v[reg] < pi2);
                nm2 = ob ? m1v[reg] : pm2;
                ni2 = ob ? i1v[reg] : pi2;
            }
            m1v[reg] = nm1; i1v[reg] = ni1;
            m2v[reg] = nm2; i2v[reg] = ni2;
        }
    }
    if (cl == 0) {   // per-half candidates for rows tile*16 + g*4+reg
#pragma unroll
        for (int reg = 0; reg < 4; ++reg) {
            const int row = tile * 16 + g * 4 + reg;
            smem_c[row * 4 + half * 2 + 0] = i1v[reg];
            smem_c[row * 4 + half * 2 + 1] = i2v[reg];
        }
    }
    __syncthreads();

    // ---- fp64 recheck of 4 candidates/row, 2 threads per candidate ----
    double* vcand = (double*)&lds_b[0][0];   // 128 doubles (k-loop done)
    {
        const int cand = tid >> 1, dh = tid & 1;
        const int row = cand >> 2, c4 = cand & 3;
        const int idx = smem_c[row * 4 + c4];
        const int t = t0 + row;
        double v = 0.0;
#pragma unroll
        for (int j = 0; j < 32; ++j) {
            const int d = dh * 32 + j;
            const double x = (double)in[bbase + (size_t)d * T_SZ + t];
            const double a = (double)w[idx * 64 + d] - x;
            v = fma(a, a, v);
        }
        v += __shfl_xor(v, 1);
        if (dh == 0) vcand[cand] = v;
    }
    __syncthreads();
    if (tid < 32) {
        const int row = tid;
        double bv = vcand[row * 4]; int bi = smem_c[row * 4];
#pragma unroll
        for (int c4 = 1; c4 < 4; ++c4) {
            const double v = vcand[row * 4 + c4];
            const int   ii = smem_c[row * 4 + c4];
            if (v < bv || (v == bv && ii < bi)) { bv = v; bi = ii; }
        }
        fin_s[row] = bi;
        atomicAdd(&hist[bi], 1);
    }
    __syncthreads();

    // ---- gather chosen codes into LDS (coalesced), pad 65 vs banks ----
    float* lds_q = (float*)&lds_b[0][0];   // 32x65 floats (vcand consumed)
#pragma unroll
    for (int r = 0; r < 8; ++r) {
        const int li = r * 256 + tid;      // 0..2047
        const int row = li >> 6, d = li & 63;
        lds_q[row * 65 + d] = w[fin_s[row] * 64 + d];
    }
    __syncthreads();

    // ---- quant write + fp64 loss partial ----
    double sq = 0.0;
#pragma unroll
    for (int it = 0; it < 8; ++it) {
        const int li = it * 256 + tid;
        const int tt = li & 31, d = li >> 5;
        const size_t go = bbase + (size_t)d * T_SZ + t0 + tt;
        const float x = in[go];
        const float q = lds_q[tt * 65 + d];
        qout[go] = q;
        const double dd = (double)q - (double)x;
        sq = fma(dd, dd, sq);
    }
    for (int off = 32; off > 0; off >>= 1) sq += __shfl_down(sq, off);
    if (lane == 0) redd[wv] = sq;

    // ---- one-hot rows: wave w writes rows w*8..w*8+8 (float2) ----
#pragma unroll 1
    for (int rr = 0; rr < 8; ++rr) {
        const int rloc = wv * 8 + rr;
        const int f = fin_s[rloc];
        float* ebase = enc + (((size_t)(n0 + rloc)) << 10);
#pragma unroll
        for (int jj = 0; jj < 8; ++jj) {
            const int col = jj * 128 + lane * 2;
            float2 v;
            v.x = (col == f)     ? 1.0f : 0.0f;
            v.y = (col + 1 == f) ? 1.0f : 0.0f;
            *(float2*)(ebase + col) = v;
        }
    }

    __syncthreads();
    if (tid == 0) {
        const double s = redd[0] + redd[1] + redd[2] + redd[3];
        atomicAdd(loss_sum, s);
        __threadfence();                       // order loss/hist before done
        const int old = atomicAdd(done, 1);
        last_s = (old == 1023) ? 1 : 0;
    }
    __syncthreads();

    // ---- last block: fused finalize (perplexity + loss scalars) ----
    if (last_s) {
        double* red = (double*)&lds_b[0][0];   // 256 doubles (lds_q consumed)
        double h = 0.0;
#pragma unroll
        for (int r = 0; r < 4; ++r) {
            const int k = r * 256 + tid;
            const int cnt = atomicAdd(&hist[k], 0);   // device-coherent read
            const double p = (double)cnt / (double)N_ROWS;
            h += p * log(p + 1e-10);
        }
        red[tid] = h;
        __syncthreads();
        for (int st = 128; st > 0; st >>= 1) {
            if (tid < st) red[tid] += red[tid + st];
            __syncthreads();
        }
        if (tid == 0) {
            out_perp[0] = (float)exp(-red[0]);
            const double ls = atomicAdd(loss_sum, 0.0);
            out_loss[0] = (float)(1.25 * (ls / (double)BCT));
        }
    }
}

extern "C" void kernel_launch(void* const* d_in, const int* in_sizes, int n_in,
                              void* d_out, int out_size, void* d_ws, size_t ws_size,
                              hipStream_t stream) {
    const float* in = (const float*)d_in[0];
    const float* w  = (const float*)d_in[1];

    float* out      = (float*)d_out;
    float* out_loss = out;                 // [0]
    float* out_q    = out + 1;             // [1, 1+BCT)
    float* out_perp = out + 1 + BCT;       // [1+BCT]
    float* out_enc  = out + 2 + BCT;       // [2+BCT, ...)

    char*   ws       = (char*)d_ws;
    int*    ws_hist  = (int*)ws;
    double* ws_loss  = (double*)(ws + 4096);
    int*    ws_done  = (int*)(ws + 4112);
    float*  ws_esq   = (float*)(ws + 8192);
    ushort* ws_wpack = (ushort*)(ws + 16384);

    k_prep  <<<32,   256, 0, stream>>>(w, ws_esq, ws_wpack, ws_hist, ws_loss,
                                       ws_done);
    k_argmin<<<1024, 256, 0, stream>>>(in, w, ws_esq, ws_wpack, ws_hist,
                                       ws_loss, ws_done, out_q, out_enc,
                                       out_loss, out_perp);
}

// Round 11
// 220.547 us; speedup vs baseline: 1.6365x; 1.6365x over previous
//
#include <hip/hip_runtime.h>
#include <cstdint>
#include <cstddef>

#define K_CODES 1024
#define D_DIM   64
#define T_SZ    2048
#define N_ROWS  32768
#define BCT     2097152

typedef const __attribute__((address_space(1))) uint32_t* gp1_t;
typedef __attribute__((address_space(3))) uint32_t*       lp3_t;
typedef __attribute__((ext_vector_type(8))) short         short8;  // 8 bf16
typedef __attribute__((ext_vector_type(4))) float         f32x4;
typedef __attribute__((ext_vector_type(4))) int           i32x4;

// ws layout (bytes):
//   [0,     4096):   hist[1024] int     (zeroed by k_prep)
//   [4096,  4104):   loss_sum double    (zeroed by k_prep)
//   [4112,  4116):   done int           (zeroed by k_prep)
//   [8192,  12288):  esq[1024] float
//   [16384, 540672): Wpack bf16 [64ct][2ks][2hl][64lane][8j] ushort (256KB)

__device__ __forceinline__ ushort bf16_rne(float f) {
    uint32_t u = __builtin_bit_cast(uint32_t, f);
    u += 0x7FFFu + ((u >> 16) & 1u);
    return (ushort)(u >> 16);
}
__device__ __forceinline__ float bf16_f(ushort h) {
    uint32_t u = ((uint32_t)h) << 16;
    return __builtin_bit_cast(float, u);
}

// 8 threads per code: esq (fp64) + W packed into MFMA B-fragment bf16 hi/lo.
__global__ __launch_bounds__(256) void k_prep(const float* __restrict__ w,
                                              float* __restrict__ esq,
                                              ushort* __restrict__ wpack,
                                              int* __restrict__ hist,
                                              double* __restrict__ loss_sum,
                                              int* __restrict__ done) {
    const int gtid = blockIdx.x * 256 + threadIdx.x;   // 0..8191
    const int k = gtid >> 3, grp = gtid & 7;
    if (gtid < K_CODES) hist[gtid] = 0;
    if (gtid == 0) { loss_sum[0] = 0.0; done[0] = 0; }
    const int ct = k >> 4, cl = k & 15;
    double s = 0.0;
#pragma unroll
    for (int jj = 0; jj < 8; ++jj) {
        const int d = grp * 8 + jj;
        const float x = w[k * 64 + d];
        s = fma((double)x, (double)x, s);
        const ushort hi = bf16_rne(x);
        const ushort lo = bf16_rne(x - bf16_f(hi));
        const int ks = d >> 5, g = (d >> 3) & 3, j = d & 7;
        const int lane = g * 16 + cl;
        const size_t base = ((size_t)(ct * 2 + ks)) * 2;
        wpack[((base + 0) * 64 + lane) * 8 + j] = hi;
        wpack[((base + 1) * 64 + lane) * 8 + j] = lo;
    }
    s += __shfl_xor(s, 1); s += __shfl_xor(s, 2); s += __shfl_xor(s, 4);
    if (grp == 0) esq[k] = (float)s;
}

// MFMA mega-kernel, R8 geometry (the L2-friendly one: FETCH was 6.2MB):
// 512 blocks x 256 thr (4 waves). Block = 64 rows x all 1024 codes; wave w
// owns one 16-row A-tile; ALL waves consume the SAME 32KB W chunk (single
// stream -> codebook stays cache-resident). 8 chunks, double-buffered via
// global_load_lds. Distances via 3 bf16-split MFMAs; fp64 top-2 recheck.
// Adds vs R8: fused last-block finalize; nontemporal enc/quant stores so
// the 142MB write stream doesn't evict wpack from L2/L3 (R9's failure).
__global__ __launch_bounds__(256, 2) void k_argmin(
        const float* __restrict__ in, const float* __restrict__ w,
        const float* __restrict__ esq, const ushort* __restrict__ wpack,
        int* __restrict__ hist, double* __restrict__ loss_sum,
        int* __restrict__ done, float* __restrict__ qout,
        float* __restrict__ enc, float* __restrict__ out_loss,
        float* __restrict__ out_perp) {
    __shared__ __align__(16) ushort lds_b[2][16384];   // 2 x 32KB (reused later)
    __shared__ float  lds_esq[K_CODES];                // 4KB
    __shared__ int    smem_i1[64], smem_i2[64];
    __shared__ int    fin_s[64];
    __shared__ double redd[4];
    __shared__ int    last_s;

    const int tid  = threadIdx.x;
    const int lane = tid & 63;
    const int wv   = tid >> 6;      // 0..3
    const int cl   = lane & 15;     // col-in-tile / row-in-A-tile
    const int g    = lane >> 4;     // k-group
    const int n0   = blockIdx.x * 64;
    const int b    = n0 >> 11;
    const int t0   = n0 & (T_SZ - 1);
    const size_t bbase = (size_t)b * 131072;

#pragma unroll
    for (int r = 0; r < 4; ++r) lds_esq[r * 256 + tid] = esq[r * 256 + tid];

    // ---- A fragments (row = lane&15, k = g*8+j; same map as B ->
    // shared k-permutation cancels in the contraction) ----
    const int t_row = t0 + wv * 16 + cl;
    short8 ah[2], al[2];
#pragma unroll
    for (int ks = 0; ks < 2; ++ks) {
        short8 h, l;
#pragma unroll
        for (int j = 0; j < 8; ++j) {
            const int d = ks * 32 + g * 8 + j;
            const float x = in[bbase + (size_t)d * T_SZ + t_row];
            const ushort hb = bf16_rne(x);
            h[j] = (short)hb;
            l[j] = (short)bf16_rne(x - bf16_f(hb));
        }
        ah[ks] = h;
        al[ks] = l;
    }

#define STAGEW(BUF, CH)                                                        \
    {                                                                          \
        _Pragma("unroll")                                                      \
        for (int r = 0; r < 8; ++r) {                                          \
            const int li = r * 256 + tid;                                      \
            const ushort* gsrc = wpack + (size_t)(CH)*16384 + (size_t)li * 8;  \
            ushort* ldst = &lds_b[BUF][li * 8];                                \
            __builtin_amdgcn_global_load_lds((gp1_t)gsrc, (lp3_t)ldst, 16, 0, 0);\
        }                                                                      \
    }

    STAGEW(0, 0)
    __syncthreads();

    f32x4 m1v = {-1e30f, -1e30f, -1e30f, -1e30f};
    f32x4 m2v = {-1e30f, -1e30f, -1e30f, -1e30f};
    i32x4 i1v = {0, 0, 0, 0};
    i32x4 i2v = {0, 0, 0, 0};

    int buf = 0;
    for (int ch = 0; ch < 8; ++ch) {
        if (ch < 7) STAGEW(buf ^ 1, ch + 1)
#pragma unroll
        for (int ctl = 0; ctl < 8; ++ctl) {
            const int ct = ch * 8 + ctl;
            const int c  = ct * 16 + cl;
            const float e2 = -0.5f * lds_esq[c];
            f32x4 accP = {e2, e2, e2, e2};
            f32x4 accQ = {0.f, 0.f, 0.f, 0.f};
#pragma unroll
            for (int ks = 0; ks < 2; ++ks) {
                const short8 bh = *(const short8*)&lds_b[buf][(((ctl * 2 + ks) * 2 + 0) * 64 + lane) * 8];
                const short8 bl = *(const short8*)&lds_b[buf][(((ctl * 2 + ks) * 2 + 1) * 64 + lane) * 8];
                accP = __builtin_amdgcn_mfma_f32_16x16x32_bf16(ah[ks], bh, accP, 0, 0, 0);
                accQ = __builtin_amdgcn_mfma_f32_16x16x32_bf16(ah[ks], bl, accQ, 0, 0, 0);
                accQ = __builtin_amdgcn_mfma_f32_16x16x32_bf16(al[ks], bh, accQ, 0, 0, 0);
            }
            // top-2 (maximize; ascending c + strict '>' keeps lowest index)
#pragma unroll
            for (int reg = 0; reg < 4; ++reg) {
                const float v = accP[reg] + accQ[reg];
                const bool gt1 = v > m1v[reg];
                const bool gt2 = v > m2v[reg];
                const float nm2 = gt1 ? m1v[reg] : (gt2 ? v : m2v[reg]);
                const int   ni2 = gt1 ? i1v[reg] : (gt2 ? c : i2v[reg]);
                m1v[reg] = gt1 ? v : m1v[reg];
                i1v[reg] = gt1 ? c : i1v[reg];
                m2v[reg] = nm2;
                i2v[reg] = ni2;
            }
        }
        __syncthreads();   // drains STAGE vmcnt + protects buf swap
        buf ^= 1;
    }

    // ---- merge top-2 across the 16 lanes of each col-group ----
#pragma unroll
    for (int off = 1; off < 16; off <<= 1) {
#pragma unroll
        for (int reg = 0; reg < 4; ++reg) {
            const float pm1 = __shfl_xor(m1v[reg], off);
            const int   pi1 = __shfl_xor(i1v[reg], off);
            const float pm2 = __shfl_xor(m2v[reg], off);
            const int   pi2 = __shfl_xor(i2v[reg], off);
            const bool ours = (m1v[reg] > pm1) ||
                              (m1v[reg] == pm1 && i1v[reg] < pi1);
            float nm1, nm2; int ni1, ni2;
            if (ours) {
                nm1 = m1v[reg]; ni1 = i1v[reg];
                const bool pb = (pm1 > m2v[reg]) ||
                                (pm1 == m2v[reg] && pi1 < i2v[reg]);
                nm2 = pb ? pm1 : m2v[reg];
                ni2 = pb ? pi1 : i2v[reg];
            } else {
                nm1 = pm1; ni1 = pi1;
                const bool ob = (m1v[reg] > pm2) ||
                                (m1v[reg] == pm2 && i1v[reg] < pi2);
                nm2 = ob ? m1v[reg] : pm2;
                ni2 = ob ? i1v[reg] : pi2;
            }
            m1v[reg] = nm1; i1v[reg] = ni1;
            m2v[reg] = nm2; i2v[reg] = ni2;
        }
    }
    if (cl == 0) {   // rows g*4+reg of this wave's 16-row tile
#pragma unroll
        for (int reg = 0; reg < 4; ++reg) {
            smem_i1[wv * 16 + g * 4 + reg] = i1v[reg];
            smem_i2[wv * 16 + g * 4 + reg] = i2v[reg];
        }
    }
    __syncthreads();

    // ---- fp64 recheck, 4 lanes per row (16 d each + shfl reduce) ----
    {
        const int rloc = wv * 16 + (lane >> 2);
        const int quar = lane & 3;
        const int ii1 = smem_i1[rloc], ii2 = smem_i2[rloc];
        const int t = t0 + rloc;
        double v1 = 0.0, v2 = 0.0;
#pragma unroll
        for (int j = 0; j < 16; ++j) {
            const int d = quar * 16 + j;
            const double x = (double)in[bbase + (size_t)d * T_SZ + t];
            const double a  = (double)w[ii1 * 64 + d] - x;
            const double cc = (double)w[ii2 * 64 + d] - x;
            v1 = fma(a, a, v1);
            v2 = fma(cc, cc, v2);
        }
        v1 += __shfl_xor(v1, 1); v1 += __shfl_xor(v1, 2);
        v2 += __shfl_xor(v2, 1); v2 += __shfl_xor(v2, 2);
        if (quar == 0) {
            int fin;
            if (v1 < v2)      fin = ii1;
            else if (v2 < v1) fin = ii2;
            else              fin = (ii1 < ii2) ? ii1 : ii2;
            fin_s[rloc] = fin;
            atomicAdd(&hist[fin], 1);
        }
    }
    __syncthreads();

    // ---- gather chosen codes into LDS (coalesced), pad 65 vs banks ----
    float* lds_q = (float*)&lds_b[0][0];   // reuse: k-loop done
#pragma unroll
    for (int r = 0; r < 16; ++r) {
        const int idx = r * 256 + tid;     // 0..4095
        const int row = idx >> 6, d = idx & 63;
        lds_q[row * 65 + d] = w[fin_s[row] * 64 + d];
    }
    __syncthreads();

    // ---- quant write (coalesced, nontemporal) + fp64 loss partial ----
    double sq = 0.0;
#pragma unroll
    for (int it = 0; it < 16; ++it) {
        const int idx = it * 256 + tid;
        const int tt = idx & 63, d = idx >> 6;
        const size_t go = bbase + (size_t)d * T_SZ + t0 + tt;
        const float x = in[go];
        const float q = lds_q[tt * 65 + d];
        __builtin_nontemporal_store(q, &qout[go]);
        const double dd = (double)q - (double)x;
        sq = fma(dd, dd, sq);
    }
    for (int off = 32; off > 0; off >>= 1) sq += __shfl_down(sq, off);
    if (lane == 0) redd[wv] = sq;

    // ---- one-hot rows (nontemporal 8B stores): wave w -> rows w*16.. ----
#pragma unroll 1
    for (int rr = 0; rr < 16; ++rr) {
        const int rloc = wv * 16 + rr;
        const int f = fin_s[rloc];
        float* ebase = enc + (((size_t)(n0 + rloc)) << 10);
#pragma unroll
        for (int jj = 0; jj < 8; ++jj) {
            const int col = jj * 128 + lane * 2;
            const uint32_t ux = (col == f)     ? 0x3F800000u : 0u;
            const uint32_t uy = (col + 1 == f) ? 0x3F800000u : 0u;
            const uint64_t pk = (uint64_t)ux | ((uint64_t)uy << 32);
            __builtin_nontemporal_store(pk, (uint64_t*)(ebase + col));
        }
    }

    __syncthreads();
    if (tid == 0) {
        const double s = redd[0] + redd[1] + redd[2] + redd[3];
        atomicAdd(loss_sum, s);
        __threadfence();                       // order loss/hist before done
        const int old = atomicAdd(done, 1);
        last_s = (old == 511) ? 1 : 0;
    }
    __syncthreads();

    // ---- last block: fused finalize (perplexity + loss scalars) ----
    if (last_s) {
        double* red = (double*)&lds_b[0][0];   // 256 doubles (lds_q consumed)
        double h = 0.0;
#pragma unroll
        for (int r = 0; r < 4; ++r) {
            const int k = r * 256 + tid;
            const int cnt = atomicAdd(&hist[k], 0);   // device-coherent read
            const double p = (double)cnt / (double)N_ROWS;
            h += p * log(p + 1e-10);
        }
        red[tid] = h;
        __syncthreads();
        for (int st = 128; st > 0; st >>= 1) {
            if (tid < st) red[tid] += red[tid + st];
            __syncthreads();
        }
        if (tid == 0) {
            out_perp[0] = (float)exp(-red[0]);
            const double ls = atomicAdd(loss_sum, 0.0);
            out_loss[0] = (float)(1.25 * (ls / (double)BCT));
        }
    }
}

extern "C" void kernel_launch(void* const* d_in, const int* in_sizes, int n_in,
                              void* d_out, int out_size, void* d_ws, size_t ws_size,
                              hipStream_t stream) {
    const float* in = (const float*)d_in[0];
    const float* w  = (const float*)d_in[1];

    float* out      = (float*)d_out;
    float* out_loss = out;                 // [0]
    float* out_q    = out + 1;             // [1, 1+BCT)
    float* out_perp = out + 1 + BCT;       // [1+BCT]
    float* out_enc  = out + 2 + BCT;       // [2+BCT, ...)

    char*   ws       = (char*)d_ws;
    int*    ws_hist  = (int*)ws;
    double* ws_loss  = (double*)(ws + 4096);
    int*    ws_done  = (int*)(ws + 4112);
    float*  ws_esq   = (float*)(ws + 8192);
    ushort* ws_wpack = (ushort*)(ws + 16384);

    k_prep  <<<32,  256, 0, stream>>>(w, ws_esq, ws_wpack, ws_hist, ws_loss,
                                      ws_done);
    k_argmin<<<512, 256, 0, stream>>>(in, w, ws_esq, ws_wpack, ws_hist,
                                      ws_loss, ws_done, out_q, out_enc,
                                      out_loss, out_perp);
}